// Round 1
// baseline (1232.917 us; speedup 1.0000x reference)
//
#include <hip/hip_runtime.h>
#include <cstddef>

// Problem constants
#define B_   16
#define C_   256
#define H_   64
#define W_   64
#define Q_   64          // channels per quadrant
#define HW_  4096
#define COUT 256
#define KK   2304        // C*9

// ---------------------------------------------------------------------------
// Kernel 1a: partial energy argmax. grid = B*4*8 blocks (8 pixel chunks),
// block = 256 threads, each thread handles 2 pixels.
// ---------------------------------------------------------------------------
__global__ __launch_bounds__(256) void energy_partial(const float* __restrict__ x,
                                                      float* __restrict__ pval,
                                                      int* __restrict__ pidx) {
    int blk   = blockIdx.x;
    int chunk = blk & 7;      // pixel chunk 0..7 (512 px each)
    int bq    = blk >> 3;     // 0..63
    int b     = bq >> 2;
    int q     = bq & 3;
    const float* base = x + ((size_t)b * C_ + (size_t)q * Q_) * HW_;
    int tid = threadIdx.x;
    int p0  = chunk * 512 + tid;     // pixel 1; pixel 2 = p0+256
    float e0 = 0.f, e1 = 0.f;
    for (int c = 0; c < Q_; ++c) {
        float v0 = base[(size_t)c * HW_ + p0];
        float v1 = base[(size_t)c * HW_ + p0 + 256];
        e0 += v0 * v0;
        e1 += v1 * v1;
    }
    float best = e0; int bi = p0;
    if (e1 > best) { best = e1; bi = p0 + 256; }
    __shared__ float sv[256];
    __shared__ int   si[256];
    sv[tid] = best; si[tid] = bi;
    __syncthreads();
    for (int s = 128; s > 0; s >>= 1) {
        if (tid < s) {
            float ov = sv[tid + s]; int oi = si[tid + s];
            if (ov > sv[tid] || (ov == sv[tid] && oi < si[tid])) {
                sv[tid] = ov; si[tid] = oi;
            }
        }
        __syncthreads();
    }
    if (tid == 0) { pval[blk] = sv[0]; pidx[blk] = si[0]; }
}

// ---------------------------------------------------------------------------
// Kernel 1b: final argmax over the 8 chunks per (b,q). 1 block, 64 threads.
// ---------------------------------------------------------------------------
__global__ __launch_bounds__(64) void energy_final(const float* __restrict__ pval,
                                                   const int* __restrict__ pidx,
                                                   int* __restrict__ lm) {
    int t = threadIdx.x;   // one per (b,q)
    float best = -3.0e38f; int bi = 0;
    for (int ch = 0; ch < 8; ++ch) {
        float v = pval[t * 8 + ch];
        int   ix = pidx[t * 8 + ch];
        if (v > best || (v == best && ix < bi)) { best = v; bi = ix; }
    }
    lm[t] = bi;
}

// ---------------------------------------------------------------------------
// Kernel 2: guided pool closed form. grid = B*C blocks, block = 256 threads,
// float4 vectorized (W=64 divisible by 4, rows never straddle a float4).
// ---------------------------------------------------------------------------
__global__ __launch_bounds__(256) void pool_kernel(const float* __restrict__ x,
                                                   const int* __restrict__ lm,
                                                   float* __restrict__ pooled) {
    int bc = blockIdx.x;            // b*256 + c
    int b  = bc >> 8;
    int c  = bc & 255;
    int q  = c >> 6;
    int l  = lm[b * 4 + q];
    int hm = l >> 6, wm = l & 63;
    const float* base = x + (size_t)bc * HW_;
    float lv = base[l];
    float L  = lv * lv;             // landmark value (squared)
    const float4* inp  = (const float4*)base;
    float4*       outp = (float4*)(pooled + (size_t)bc * HW_);
    int tid = threadIdx.x;
    bool hle = (q < 2);             // q0,q1: h <= hm ; q2,q3: h >= hm
    bool wle = ((q & 1) == 0);      // q0,q2: w <= wm ; q1,q3: w >= wm
    for (int i = tid; i < HW_ / 4; i += 256) {
        float4 v = inp[i];
        int p0 = i * 4;
        int h  = p0 >> 6;
        int w0 = p0 & 63;
        float4 s;
        s.x = v.x * v.x; s.y = v.y * v.y; s.z = v.z * v.z; s.w = v.w * v.w;
        bool hok = hle ? (h <= hm) : (h >= hm);
        if (hok) {
            bool w_ok0 = wle ? (w0 + 0 <= wm) : (w0 + 0 >= wm);
            bool w_ok1 = wle ? (w0 + 1 <= wm) : (w0 + 1 >= wm);
            bool w_ok2 = wle ? (w0 + 2 <= wm) : (w0 + 2 >= wm);
            bool w_ok3 = wle ? (w0 + 3 <= wm) : (w0 + 3 >= wm);
            if (w_ok0 && L > s.x) s.x = L;
            if (w_ok1 && L > s.y) s.y = L;
            if (w_ok2 && L > s.z) s.z = L;
            if (w_ok3 && L > s.w) s.w = L;
        }
        outp[i] = s;
    }
}

// ---------------------------------------------------------------------------
// Kernel 3: weight transpose -> Wt[k][co], k = ci*9 + kh*3 + kw.
// ---------------------------------------------------------------------------
__global__ __launch_bounds__(256) void wt_transpose(const float* __restrict__ w,
                                                    float* __restrict__ wt) {
    int k  = blockIdx.x;    // 0..2303
    int co = threadIdx.x;   // 0..255
    wt[(size_t)k * COUT + co] = w[(size_t)co * KK + k];
}

// ---------------------------------------------------------------------------
// Kernel 4: implicit-GEMM 3x3 conv, fp32 VALU.
// Block tile: 128 co x 128 px (2 image rows). 256 threads, 8x8 per thread.
// grid: (512 pixel tiles, 2 co tiles)
// ---------------------------------------------------------------------------
__global__ __launch_bounds__(256, 4) void conv_kernel(const float* __restrict__ pooled,
                                                      const float* __restrict__ Wt,
                                                      const float* __restrict__ bias,
                                                      float* __restrict__ out) {
    int pt = blockIdx.x;            // pixel tile: b(16) * hpair(32)
    int b  = pt >> 5;
    int h0 = (pt & 31) * 2;
    int co_base = blockIdx.y * 128;

    __shared__ float As[9][128];    // k-inner x co
    __shared__ float Bs[9][132];    // k-inner x px (pad 132: keeps 16B align)

    int tid = threadIdx.x;
    int tx  = tid & 15;             // px group
    int ty  = tid >> 4;             // co group
    int px0 = tx * 8;
    int co0 = ty * 8;

    float acc[8][8];
#pragma unroll
    for (int u = 0; u < 8; ++u)
#pragma unroll
        for (int v = 0; v < 8; ++v) acc[u][v] = 0.f;

    const float* pb = pooled + (size_t)b * C_ * HW_;

    for (int ci = 0; ci < C_; ++ci) {
        // stage A: 9*128 weights for this ci
        for (int idx = tid; idx < 9 * 128; idx += 256) {
            int j   = idx >> 7;
            int col = idx & 127;
            As[j][col] = Wt[((size_t)ci * 9 + j) * COUT + co_base + col];
        }
        // stage B: 9*128 im2col values for this ci
        for (int idx = tid; idx < 9 * 128; idx += 256) {
            int j  = idx >> 7;
            int px = idx & 127;
            int kh = j / 3;
            int kw = j - kh * 3;
            int r  = px >> 6;
            int w  = px & 63;
            int hh = h0 + r + kh - 1;
            int ww = w + kw - 1;
            float v = 0.f;
            if (hh >= 0 && hh < H_ && ww >= 0 && ww < W_)
                v = pb[(size_t)ci * HW_ + hh * W_ + ww];
            Bs[j][px] = v;
        }
        __syncthreads();
#pragma unroll
        for (int j = 0; j < 9; ++j) {
            float a[8], bv[8];
#pragma unroll
            for (int u = 0; u < 8; ++u) a[u] = As[j][co0 + u];
#pragma unroll
            for (int u = 0; u < 8; ++u) bv[u] = Bs[j][px0 + u];
#pragma unroll
            for (int u = 0; u < 8; ++u)
#pragma unroll
                for (int v = 0; v < 8; ++v)
                    acc[u][v] += a[u] * bv[v];
        }
        __syncthreads();
    }

    // epilogue: add bias, write out[b, co, h, w]
#pragma unroll
    for (int u = 0; u < 8; ++u) {
        int co = co_base + co0 + u;
        float bs = bias[co];
#pragma unroll
        for (int v = 0; v < 8; ++v) {
            int px = px0 + v;
            int r  = px >> 6;
            int w  = px & 63;
            out[(((size_t)b * COUT + co) * H_ + (h0 + r)) * W_ + w] = acc[u][v] + bs;
        }
    }
}

// ---------------------------------------------------------------------------
extern "C" void kernel_launch(void* const* d_in, const int* in_sizes, int n_in,
                              void* d_out, int out_size, void* d_ws, size_t ws_size,
                              hipStream_t stream) {
    const float* x      = (const float*)d_in[0];
    const float* weight = (const float*)d_in[1];
    const float* bias   = (const float*)d_in[2];
    float* out = (float*)d_out;

    char* ws = (char*)d_ws;
    int*   lm     = (int*)ws;                       // 64 ints
    float* pval   = (float*)(ws + 256);             // 512 floats
    int*   pidx   = (int*)(ws + 256 + 2048);        // 512 ints
    float* Wt     = (float*)(ws + 8192);            // 2304*256 floats
    float* pooled = (float*)(ws + 8192 + (size_t)KK * COUT * 4);  // B*C*H*W floats

    hipLaunchKernelGGL(energy_partial, dim3(512), dim3(256), 0, stream, x, pval, pidx);
    hipLaunchKernelGGL(energy_final, dim3(1), dim3(64), 0, stream, pval, pidx, lm);
    hipLaunchKernelGGL(pool_kernel, dim3(B_ * C_), dim3(256), 0, stream, x, lm, pooled);
    hipLaunchKernelGGL(wt_transpose, dim3(KK), dim3(256), 0, stream, weight, Wt);
    hipLaunchKernelGGL(conv_kernel, dim3(512, 2), dim3(256), 0, stream, pooled, Wt, bias, out);
}

// Round 2
// 239.172 us; speedup vs baseline: 5.1549x; 5.1549x over previous
//
#include <hip/hip_runtime.h>
#include <cstddef>

// Problem constants
#define B_   16
#define C_   256
#define H_   64
#define W_   64
#define Q_   64
#define HW_  4096
#define COUT 256

typedef __attribute__((ext_vector_type(8)))  short bf16x8;
typedef __attribute__((ext_vector_type(16))) float f32x16;

static __device__ __forceinline__ unsigned short f2bf(float f) {
    unsigned int u = __float_as_uint(f);
    u += 0x7fffu + ((u >> 16) & 1u);          // RNE
    return (unsigned short)(u >> 16);
}

// ---------------------------------------------------------------------------
// Kernel 1a: partial energy argmax (unchanged from round 1 — verified).
// ---------------------------------------------------------------------------
__global__ __launch_bounds__(256) void energy_partial(const float* __restrict__ x,
                                                      float* __restrict__ pval,
                                                      int* __restrict__ pidx) {
    int blk   = blockIdx.x;
    int chunk = blk & 7;
    int bq    = blk >> 3;
    int b     = bq >> 2;
    int q     = bq & 3;
    const float* base = x + ((size_t)b * C_ + (size_t)q * Q_) * HW_;
    int tid = threadIdx.x;
    int p0  = chunk * 512 + tid;
    float e0 = 0.f, e1 = 0.f;
    for (int c = 0; c < Q_; ++c) {
        float v0 = base[(size_t)c * HW_ + p0];
        float v1 = base[(size_t)c * HW_ + p0 + 256];
        e0 += v0 * v0;
        e1 += v1 * v1;
    }
    float best = e0; int bi = p0;
    if (e1 > best) { best = e1; bi = p0 + 256; }
    __shared__ float sv[256];
    __shared__ int   si[256];
    sv[tid] = best; si[tid] = bi;
    __syncthreads();
    for (int s = 128; s > 0; s >>= 1) {
        if (tid < s) {
            float ov = sv[tid + s]; int oi = si[tid + s];
            if (ov > sv[tid] || (ov == sv[tid] && oi < si[tid])) {
                sv[tid] = ov; si[tid] = oi;
            }
        }
        __syncthreads();
    }
    if (tid == 0) { pval[blk] = sv[0]; pidx[blk] = si[0]; }
}

__global__ __launch_bounds__(64) void energy_final(const float* __restrict__ pval,
                                                   const int* __restrict__ pidx,
                                                   int* __restrict__ lm) {
    int t = threadIdx.x;
    float best = -3.0e38f; int bi = 0;
    for (int ch = 0; ch < 8; ++ch) {
        float v = pval[t * 8 + ch];
        int   ix = pidx[t * 8 + ch];
        if (v > best || (v == best && ix < bi)) { best = v; bi = ix; }
    }
    lm[t] = bi;
}

// ---------------------------------------------------------------------------
// Kernel 2: guided pool -> NHWC bf16.  grid = (b,h) = 1024 blocks, 256 thr.
// Phase 1: coalesced NCHW reads, squared + landmark-rect max, LDS transpose.
// Phase 2: coalesced NHWC bf16 writes (c contiguous).
// ---------------------------------------------------------------------------
__global__ __launch_bounds__(256) void pool_nhwc(const float* __restrict__ x,
                                                 const int* __restrict__ lm,
                                                 unsigned short* __restrict__ pooled) {
    int blk = blockIdx.x;
    int b = blk >> 6, h = blk & 63;
    int tid = threadIdx.x;
    int ty = tid >> 6, tx = tid & 63;
    __shared__ unsigned short tile[64][260];   // [w][c], pad 260 vs 256
    for (int cc = 0; cc < 64; ++cc) {
        int c = cc * 4 + ty;
        int q = c >> 6;
        int l = lm[b * 4 + q];
        int hm = l >> 6, wm = l & 63;
        float lv = x[((size_t)(b * 256 + c) * 64 + hm) * 64 + wm];
        float L = lv * lv;
        float v = x[((size_t)(b * 256 + c) * 64 + h) * 64 + tx];
        float s = v * v;
        bool hok = (q < 2) ? (h <= hm) : (h >= hm);
        bool wok = ((q & 1) == 0) ? (tx <= wm) : (tx >= wm);
        if (hok && wok && L > s) s = L;
        tile[tx][c] = f2bf(s);
    }
    __syncthreads();
    size_t base = (size_t)(b * 64 + h) * 64 * 256;
    for (int w = 0; w < 64; ++w) {
        pooled[base + (size_t)w * 256 + tid] = tile[w][tid];
    }
}

// ---------------------------------------------------------------------------
// Kernel 3: weight pack -> fragment-ordered bf16.
// Block blk = (((j*8+cib)*2+s)*8+cog); 64 lanes; lane's 8 values are the exact
// A-fragment for mfma_32x32x16: co = cog*32+(lane&31), k = cib*32+s*16+(lane>>5)*8+jj.
// ---------------------------------------------------------------------------
__global__ __launch_bounds__(64) void wt_pack(const float* __restrict__ w,
                                              unsigned short* __restrict__ wa) {
    int blk  = blockIdx.x;
    int lane = threadIdx.x;
    int cog = blk & 7;
    int s   = (blk >> 3) & 1;
    int cib = (blk >> 4) & 7;
    int j   = blk >> 7;
    int co  = cog * 32 + (lane & 31);
    int k0  = cib * 32 + s * 16 + (lane >> 5) * 8;
    union { unsigned short us[8]; int4 v; } u;
#pragma unroll
    for (int jj = 0; jj < 8; ++jj) {
        int ci = k0 + jj;
        u.us[jj] = f2bf(w[(size_t)(co * 256 + ci) * 9 + j]);
    }
    *(int4*)(wa + ((size_t)blk * 64 + lane) * 8) = u.v;
}

// ---------------------------------------------------------------------------
// Kernel 4: implicit-GEMM conv, bf16 MFMA (v_mfma_f32_32x32x16_bf16).
// Block: 256 thr = 4 waves; block tile 256co x 128px (2 image rows);
// wave tile 128co x 64px (wy = co half, wx = image row).
// B staged in LDS per 32-ci block (4 rows x 66 cols x 40-pad ci, bf16);
// A fragments read directly from global (fragment-packed, L2 resident).
// ---------------------------------------------------------------------------
__global__ __launch_bounds__(256, 2) void conv_mfma(const unsigned short* __restrict__ pooled,
                                                    const unsigned short* __restrict__ wa,
                                                    const float* __restrict__ bias,
                                                    float* __restrict__ out) {
    int pt = blockIdx.x;
    int b  = pt >> 5;
    int h0 = (pt & 31) * 2;
    int tid  = threadIdx.x;
    int lane = tid & 63;
    int wv   = tid >> 6;
    int wy = wv >> 1, wx = wv & 1;
    int l31 = lane & 31, q = lane >> 5;

    __shared__ unsigned short Bs[4 * 66 * 40];

    f32x16 acc[4][2];
#pragma unroll
    for (int mt = 0; mt < 4; ++mt)
#pragma unroll
        for (int nt = 0; nt < 2; ++nt)
#pragma unroll
            for (int r = 0; r < 16; ++r) acc[mt][nt][r] = 0.f;

    int sr = tid >> 6, sc = tid & 63;         // primary staging slot
    int sr2 = tid >> 1, sc2 = 64 + (tid & 1); // extra cols 64,65 (tid<8)

    for (int cib = 0; cib < 8; ++cib) {
        // ---- stage B tile ----
        {
            int grow = h0 - 1 + sr;
            int gcol = sc - 1;
            int4 v0 = {0,0,0,0}, v1 = {0,0,0,0}, v2 = {0,0,0,0}, v3 = {0,0,0,0};
            if ((unsigned)grow < 64u && (unsigned)gcol < 64u) {
                const int4* src = (const int4*)(pooled +
                    (((size_t)(b * 64 + grow) * 64 + gcol) * 256 + cib * 32));
                v0 = src[0]; v1 = src[1]; v2 = src[2]; v3 = src[3];
            }
            int4* dst = (int4*)(Bs + (sr * 66 + sc) * 40);
            dst[0] = v0; dst[1] = v1; dst[2] = v2; dst[3] = v3;
        }
        if (tid < 8) {
            int grow = h0 - 1 + sr2;
            int gcol = sc2 - 1;
            int4 v0 = {0,0,0,0}, v1 = {0,0,0,0}, v2 = {0,0,0,0}, v3 = {0,0,0,0};
            if ((unsigned)grow < 64u && (unsigned)gcol < 64u) {
                const int4* src = (const int4*)(pooled +
                    (((size_t)(b * 64 + grow) * 64 + gcol) * 256 + cib * 32));
                v0 = src[0]; v1 = src[1]; v2 = src[2]; v3 = src[3];
            }
            int4* dst = (int4*)(Bs + (sr2 * 66 + sc2) * 40);
            dst[0] = v0; dst[1] = v1; dst[2] = v2; dst[3] = v3;
        }
        __syncthreads();

        // ---- MFMA over 9 taps x 2 K-halves ----
#pragma unroll
        for (int j = 0; j < 9; ++j) {
            int dh = j / 3 - 1, dw = j % 3 - 1;
            int r = wx + dh + 1;              // tile row 0..3
            int w0 = l31 + dw + 1;            // tile col for nt=0
#pragma unroll
            for (int s = 0; s < 2; ++s) {
                const bf16x8* ap = (const bf16x8*)(wa +
                    ((((size_t)((j * 8 + cib) * 2 + s)) * 8 + wy * 4) * 64 + lane) * 8);
                bf16x8 a0 = ap[0];
                bf16x8 a1 = ap[64];
                bf16x8 a2 = ap[128];
                bf16x8 a3 = ap[192];
                bf16x8 b0 = *(const bf16x8*)(Bs + ((r * 66 + w0) * 40 + s * 16 + q * 8));
                bf16x8 b1 = *(const bf16x8*)(Bs + ((r * 66 + w0 + 32) * 40 + s * 16 + q * 8));
                acc[0][0] = __builtin_amdgcn_mfma_f32_32x32x16_bf16(a0, b0, acc[0][0], 0, 0, 0);
                acc[0][1] = __builtin_amdgcn_mfma_f32_32x32x16_bf16(a0, b1, acc[0][1], 0, 0, 0);
                acc[1][0] = __builtin_amdgcn_mfma_f32_32x32x16_bf16(a1, b0, acc[1][0], 0, 0, 0);
                acc[1][1] = __builtin_amdgcn_mfma_f32_32x32x16_bf16(a1, b1, acc[1][1], 0, 0, 0);
                acc[2][0] = __builtin_amdgcn_mfma_f32_32x32x16_bf16(a2, b0, acc[2][0], 0, 0, 0);
                acc[2][1] = __builtin_amdgcn_mfma_f32_32x32x16_bf16(a2, b1, acc[2][1], 0, 0, 0);
                acc[3][0] = __builtin_amdgcn_mfma_f32_32x32x16_bf16(a3, b0, acc[3][0], 0, 0, 0);
                acc[3][1] = __builtin_amdgcn_mfma_f32_32x32x16_bf16(a3, b1, acc[3][1], 0, 0, 0);
            }
        }
        __syncthreads();
    }

    // ---- epilogue ----
    int h = h0 + wx;
#pragma unroll
    for (int mt = 0; mt < 4; ++mt) {
#pragma unroll
        for (int nt = 0; nt < 2; ++nt) {
#pragma unroll
            for (int r = 0; r < 16; ++r) {
                int row = (r & 3) + 8 * (r >> 2) + 4 * q;
                int co  = wy * 128 + mt * 32 + row;
                int w   = nt * 32 + l31;
                out[(((size_t)(b * 256 + co)) * 64 + h) * 64 + w] = acc[mt][nt][r] + bias[co];
            }
        }
    }
}

// ---------------------------------------------------------------------------
extern "C" void kernel_launch(void* const* d_in, const int* in_sizes, int n_in,
                              void* d_out, int out_size, void* d_ws, size_t ws_size,
                              hipStream_t stream) {
    const float* x      = (const float*)d_in[0];
    const float* weight = (const float*)d_in[1];
    const float* bias   = (const float*)d_in[2];
    float* out = (float*)d_out;

    char* ws = (char*)d_ws;
    int*            lmp    = (int*)ws;                        // 64 ints
    float*          pval   = (float*)(ws + 256);              // 512 floats
    int*            pidx   = (int*)(ws + 256 + 2048);         // 512 ints
    unsigned short* Wa     = (unsigned short*)(ws + 8192);    // 1152*64*8 bf16 = 1.18 MB
    unsigned short* pooled = (unsigned short*)(ws + 8192 + 1179648); // NHWC bf16, 33.55 MB

    hipLaunchKernelGGL(energy_partial, dim3(512), dim3(256), 0, stream, x, pval, pidx);
    hipLaunchKernelGGL(energy_final, dim3(1), dim3(64), 0, stream, pval, pidx, lmp);
    hipLaunchKernelGGL(pool_nhwc, dim3(1024), dim3(256), 0, stream, x, lmp, pooled);
    hipLaunchKernelGGL(wt_pack, dim3(1152), dim3(64), 0, stream, weight, Wa);
    hipLaunchKernelGGL(conv_mfma, dim3(512), dim3(256), 0, stream, pooled, Wa, bias, out);
}

// Round 3
// 237.316 us; speedup vs baseline: 5.1952x; 1.0078x over previous
//
#include <hip/hip_runtime.h>
#include <cstddef>

#define B_   16
#define C_   256
#define HW_  4096

typedef __attribute__((ext_vector_type(8)))  short bf16x8;
typedef __attribute__((ext_vector_type(16))) float f32x16;

static __device__ __forceinline__ unsigned short f2bf(float f) {
    unsigned int u = __float_as_uint(f);
    u += 0x7fffu + ((u >> 16) & 1u);          // RNE
    return (unsigned short)(u >> 16);
}

// ---------------------------------------------------------------------------
// Kernel E: fused square + NCHW->NHWC bf16 convert + per-(b,q,h) energy
// argmax partials. grid = (b,h) = 1024 blocks x 256 thr.
// wave = fixed layer, lanes = w (coalesced 256B reads).
// ---------------------------------------------------------------------------
__global__ __launch_bounds__(256) void fused_energy(const float* __restrict__ x,
                                                    unsigned short* __restrict__ xsqN,
                                                    float* __restrict__ pval,
                                                    int* __restrict__ pidx) {
    int blk = blockIdx.x;
    int b = blk >> 6, h = blk & 63;
    int tid = threadIdx.x;
    int w = tid & 63, layer = tid >> 6;
    __shared__ float earr[4][4][64];
    float e0 = 0.f, e1 = 0.f, e2 = 0.f, e3 = 0.f;
    const float* xb = x + (size_t)b * C_ * HW_ + h * 64 + w;
    unsigned short* ob = xsqN + ((size_t)(b * 64 + h) * 64 + w) * 256;
#pragma unroll
    for (int i = 0; i < 8; ++i) {
        int g  = i * 4 + layer;          // channel group (8 ch each)
        int c0 = g * 8;
        union { unsigned short us[8]; int4 v; } u;
        float es = 0.f;
#pragma unroll
        for (int k = 0; k < 8; ++k) {
            float v = xb[(size_t)(c0 + k) * HW_];
            float s = v * v;
            es += s;
            u.us[k] = f2bf(s);
        }
        *(int4*)(ob + c0) = u.v;
        // quadrant of this group = (32i+8*layer)>>6 = i>>1 (layer<4)
        if ((i >> 1) == 0) e0 += es;
        else if ((i >> 1) == 1) e1 += es;
        else if ((i >> 1) == 2) e2 += es;
        else e3 += es;
    }
    earr[layer][0][w] = e0; earr[layer][1][w] = e1;
    earr[layer][2][w] = e2; earr[layer][3][w] = e3;
    __syncthreads();
    int q = tid >> 6;
    float ev = earr[0][q][w] + earr[1][q][w] + earr[2][q][w] + earr[3][q][w];
    int ix = h * 64 + w;
#pragma unroll
    for (int off = 32; off; off >>= 1) {
        float ov = __shfl_down(ev, off);
        int   oi = __shfl_down(ix, off);
        if (ov > ev || (ov == ev && oi < ix)) { ev = ov; ix = oi; }
    }
    if ((tid & 63) == 0) {
        pval[(b * 64 + h) * 4 + q] = ev;
        pidx[(b * 64 + h) * 4 + q] = ix;
    }
}

// ---------------------------------------------------------------------------
// Final argmax over h per (b,q). 1 block x 64 threads.
// ---------------------------------------------------------------------------
__global__ __launch_bounds__(64) void energy_final(const float* __restrict__ pval,
                                                   const int* __restrict__ pidx,
                                                   int* __restrict__ lm) {
    int t = threadIdx.x;
    int b = t >> 2, q = t & 3;
    float best = -1.f; int bi = 1 << 30;
    for (int h = 0; h < 64; ++h) {
        float v = pval[(b * 64 + h) * 4 + q];
        int  ix = pidx[(b * 64 + h) * 4 + q];
        if (v > best || (v == best && ix < bi)) { best = v; bi = ix; }
    }
    lm[t] = bi;
}

// ---------------------------------------------------------------------------
// Landmark value table Lval[b][c] (bf16). 16 blocks x 256 thr.
// ---------------------------------------------------------------------------
__global__ __launch_bounds__(256) void lval_kernel(const unsigned short* __restrict__ xsqN,
                                                   const int* __restrict__ lm,
                                                   unsigned short* __restrict__ Lval) {
    int t = blockIdx.x * 256 + threadIdx.x;   // b*256 + c
    int b = t >> 8, c = t & 255, q = c >> 6;
    int l = lm[b * 4 + q];
    Lval[t] = xsqN[((size_t)((b * 64 + (l >> 6)) * 64 + (l & 63))) * 256 + c];
}

// ---------------------------------------------------------------------------
// Weight pack -> fragment-ordered bf16 (unchanged from R2, verified).
// ---------------------------------------------------------------------------
__global__ __launch_bounds__(64) void wt_pack(const float* __restrict__ w,
                                              unsigned short* __restrict__ wa) {
    int blk  = blockIdx.x;
    int lane = threadIdx.x;
    int cog = blk & 7;
    int s   = (blk >> 3) & 1;
    int cib = (blk >> 4) & 7;
    int j   = blk >> 7;
    int co  = cog * 32 + (lane & 31);
    int k0  = cib * 32 + s * 16 + (lane >> 5) * 8;
    union { unsigned short us[8]; int4 v; } u;
#pragma unroll
    for (int jj = 0; jj < 8; ++jj) {
        int ci = k0 + jj;
        u.us[jj] = f2bf(w[(size_t)(co * 256 + ci) * 9 + j]);
    }
    *(int4*)(wa + ((size_t)blk * 64 + lane) * 8) = u.v;
}

// ---------------------------------------------------------------------------
// Conv: implicit-GEMM bf16 MFMA with fused guided-pool rect-max in staging.
// Block: 512 thr = 8 waves; tile 256co x 256px (4 rows). Wave: 128co x 64px.
// Grid: 256 blocks = 1 block/CU. Double-buffered LDS, register prefetch.
// ---------------------------------------------------------------------------
__global__ __launch_bounds__(512, 2) void conv_mfma(const unsigned short* __restrict__ xsqN,
                                                    const unsigned short* __restrict__ wa,
                                                    const float* __restrict__ bias,
                                                    const int* __restrict__ lm,
                                                    const unsigned short* __restrict__ Lval,
                                                    float* __restrict__ out) {
    int pt = blockIdx.x;              // b*16 + hq
    int b  = pt >> 4;
    int h0 = (pt & 15) * 4;
    int tid  = threadIdx.x;
    int lane = tid & 63;
    int wv   = tid >> 6;
    int wy = wv >> 2, wx = wv & 3;    // co half / image row
    int l31 = lane & 31, qh = lane >> 5;

    __shared__ unsigned short Bs[2][6 * 66 * 40];

    f32x16 acc[4][2];
#pragma unroll
    for (int mt = 0; mt < 4; ++mt)
#pragma unroll
        for (int nt = 0; nt < 2; ++nt)
#pragma unroll
            for (int r = 0; r < 16; ++r) acc[mt][nt][r] = 0.f;

    // ---- staging helpers (idx in [0,1584): pr=idx/264, pc=(idx%264)>>2, part=idx&3)
    int4 sv[4];

    // prologue: load + rect-max + write cib=0 into buf 0
    {
        const int cib = 0;
#pragma unroll
        for (int t2 = 0; t2 < 4; ++t2) {
            int idx = tid + t2 * 512;
            int4 v = {0, 0, 0, 0};
            if (idx < 1584) {
                int pr = idx / 264; int rem = idx - pr * 264;
                int pc = rem >> 2;  int part = rem & 3;
                int grow = h0 - 1 + pr, gcol = pc - 1;
                if ((unsigned)grow < 64u && (unsigned)gcol < 64u)
                    v = *(const int4*)(xsqN + (((size_t)(b * 64 + grow) * 64 + gcol) * 256 + cib * 32 + part * 8));
            }
            sv[t2] = v;
        }
        int l = lm[b * 4 + (cib >> 1)];
        int hm = l >> 6, wm = l & 63;
        bool qhle = (cib >> 1) < 2;
        bool qwle = ((cib >> 1) & 1) == 0;
#pragma unroll
        for (int t2 = 0; t2 < 4; ++t2) {
            int idx = tid + t2 * 512;
            if (idx < 1584) {
                int pr = idx / 264; int rem = idx - pr * 264;
                int pc = rem >> 2;  int part = rem & 3;
                int grow = h0 - 1 + pr, gcol = pc - 1;
                union { int4 v; unsigned short us[8]; } u; u.v = sv[t2];
                bool inb = ((unsigned)grow < 64u) && ((unsigned)gcol < 64u);
                bool hok = qhle ? (grow <= hm) : (grow >= hm);
                bool wok = qwle ? (gcol <= wm) : (gcol >= wm);
                if (inb && hok && wok) {
                    union { int4 v; unsigned short us[8]; } Lu;
                    Lu.v = *(const int4*)(Lval + b * 256 + cib * 32 + part * 8);
#pragma unroll
                    for (int k = 0; k < 8; ++k)
                        if (Lu.us[k] > u.us[k]) u.us[k] = Lu.us[k];
                }
                *(int4*)(&Bs[0][(pr * 66 + pc) * 40 + part * 8]) = u.v;
            }
        }
    }
    __syncthreads();

    for (int cib = 0; cib < 8; ++cib) {
        int cur = cib & 1;
        // ---- issue prefetch loads for cib+1 (latency hidden behind MFMAs) ----
        if (cib < 7) {
            int nc = cib + 1;
#pragma unroll
            for (int t2 = 0; t2 < 4; ++t2) {
                int idx = tid + t2 * 512;
                int4 v = {0, 0, 0, 0};
                if (idx < 1584) {
                    int pr = idx / 264; int rem = idx - pr * 264;
                    int pc = rem >> 2;  int part = rem & 3;
                    int grow = h0 - 1 + pr, gcol = pc - 1;
                    if ((unsigned)grow < 64u && (unsigned)gcol < 64u)
                        v = *(const int4*)(xsqN + (((size_t)(b * 64 + grow) * 64 + gcol) * 256 + nc * 32 + part * 8));
                }
                sv[t2] = v;
            }
        }

        // ---- MFMA phase on buf[cur] ----
        const unsigned short* Bb = &Bs[cur][0];
#pragma unroll
        for (int j = 0; j < 9; ++j) {
            int dh = j / 3 - 1, dw = j % 3 - 1;
            int r  = wx + dh + 1;
            int w0 = l31 + dw + 1;
#pragma unroll
            for (int s = 0; s < 2; ++s) {
                const bf16x8* ap = (const bf16x8*)(wa +
                    ((((size_t)((j * 8 + cib) * 2 + s)) * 8 + wy * 4) * 64 + lane) * 8);
                bf16x8 a0 = ap[0];
                bf16x8 a1 = ap[64];
                bf16x8 a2 = ap[128];
                bf16x8 a3 = ap[192];
                bf16x8 b0 = *(const bf16x8*)(Bb + (r * 66 + w0) * 40 + s * 16 + qh * 8);
                bf16x8 b1 = *(const bf16x8*)(Bb + (r * 66 + w0 + 32) * 40 + s * 16 + qh * 8);
                acc[0][0] = __builtin_amdgcn_mfma_f32_32x32x16_bf16(a0, b0, acc[0][0], 0, 0, 0);
                acc[0][1] = __builtin_amdgcn_mfma_f32_32x32x16_bf16(a0, b1, acc[0][1], 0, 0, 0);
                acc[1][0] = __builtin_amdgcn_mfma_f32_32x32x16_bf16(a1, b0, acc[1][0], 0, 0, 0);
                acc[1][1] = __builtin_amdgcn_mfma_f32_32x32x16_bf16(a1, b1, acc[1][1], 0, 0, 0);
                acc[2][0] = __builtin_amdgcn_mfma_f32_32x32x16_bf16(a2, b0, acc[2][0], 0, 0, 0);
                acc[2][1] = __builtin_amdgcn_mfma_f32_32x32x16_bf16(a2, b1, acc[2][1], 0, 0, 0);
                acc[3][0] = __builtin_amdgcn_mfma_f32_32x32x16_bf16(a3, b0, acc[3][0], 0, 0, 0);
                acc[3][1] = __builtin_amdgcn_mfma_f32_32x32x16_bf16(a3, b1, acc[3][1], 0, 0, 0);
            }
        }

        // ---- rect-max + ds_write for cib+1 into the other buffer ----
        if (cib < 7) {
            int nc = cib + 1;
            int l = lm[b * 4 + (nc >> 1)];
            int hm = l >> 6, wm = l & 63;
            bool qhle = (nc >> 1) < 2;
            bool qwle = ((nc >> 1) & 1) == 0;
            unsigned short* Bw = &Bs[1 - cur][0];
#pragma unroll
            for (int t2 = 0; t2 < 4; ++t2) {
                int idx = tid + t2 * 512;
                if (idx < 1584) {
                    int pr = idx / 264; int rem = idx - pr * 264;
                    int pc = rem >> 2;  int part = rem & 3;
                    int grow = h0 - 1 + pr, gcol = pc - 1;
                    union { int4 v; unsigned short us[8]; } u; u.v = sv[t2];
                    bool inb = ((unsigned)grow < 64u) && ((unsigned)gcol < 64u);
                    bool hok = qhle ? (grow <= hm) : (grow >= hm);
                    bool wok = qwle ? (gcol <= wm) : (gcol >= wm);
                    if (inb && hok && wok) {
                        union { int4 v; unsigned short us[8]; } Lu;
                        Lu.v = *(const int4*)(Lval + b * 256 + nc * 32 + part * 8);
#pragma unroll
                        for (int k = 0; k < 8; ++k)
                            if (Lu.us[k] > u.us[k]) u.us[k] = Lu.us[k];
                    }
                    *(int4*)(&Bw[(pr * 66 + pc) * 40 + part * 8]) = u.v;
                }
            }
        }
        __syncthreads();
    }

    // ---- epilogue ----
    int h = h0 + wx;
#pragma unroll
    for (int mt = 0; mt < 4; ++mt) {
#pragma unroll
        for (int nt = 0; nt < 2; ++nt) {
#pragma unroll
            for (int r = 0; r < 16; ++r) {
                int row = (r & 3) + 8 * (r >> 2) + 4 * qh;
                int co  = wy * 128 + mt * 32 + row;
                int w   = nt * 32 + l31;
                out[(((size_t)(b * 256 + co)) * 64 + h) * 64 + w] = acc[mt][nt][r] + bias[co];
            }
        }
    }
}

// ---------------------------------------------------------------------------
extern "C" void kernel_launch(void* const* d_in, const int* in_sizes, int n_in,
                              void* d_out, int out_size, void* d_ws, size_t ws_size,
                              hipStream_t stream) {
    const float* x      = (const float*)d_in[0];
    const float* weight = (const float*)d_in[1];
    const float* bias   = (const float*)d_in[2];
    float* out = (float*)d_out;

    char* ws = (char*)d_ws;
    int*            lmp  = (int*)ws;                         // 64 ints @0
    float*          pval = (float*)(ws + 256);               // 4096 f  @256
    int*            pidx = (int*)(ws + 256 + 16384);         // 4096 i
    unsigned short* Lval = (unsigned short*)(ws + 256 + 32768);  // 4096 ush (8KB)
    unsigned short* Wa   = (unsigned short*)(ws + 49152);    // 1152*64*8 bf16 = 1.18MB
    unsigned short* xsqN = (unsigned short*)(ws + 49152 + 1179648); // NHWC bf16, 33.55MB

    hipLaunchKernelGGL(fused_energy, dim3(1024), dim3(256), 0, stream, x, xsqN, pval, pidx);
    hipLaunchKernelGGL(energy_final, dim3(1), dim3(64), 0, stream, pval, pidx, lmp);
    hipLaunchKernelGGL(lval_kernel, dim3(16), dim3(256), 0, stream, xsqN, lmp, Lval);
    hipLaunchKernelGGL(wt_pack, dim3(1152), dim3(64), 0, stream, weight, Wa);
    hipLaunchKernelGGL(conv_mfma, dim3(256), dim3(512), 0, stream, xsqN, Wa, bias, lmp, Lval, out);
}

// Round 4
// 198.506 us; speedup vs baseline: 6.2110x; 1.1955x over previous
//
#include <hip/hip_runtime.h>
#include <cstddef>

#define B_   16
#define C_   256
#define HW_  4096

typedef __attribute__((ext_vector_type(8)))  short bf16x8;
typedef __attribute__((ext_vector_type(16))) float f32x16;

static __device__ __forceinline__ unsigned short f2bf(float f) {
    unsigned int u = __float_as_uint(f);
    u += 0x7fffu + ((u >> 16) & 1u);          // RNE
    return (unsigned short)(u >> 16);
}

// ---------------------------------------------------------------------------
// Kernel E: fused square + NCHW->NHWC bf16 + per-(b,q,h) energy argmax
// partials. grid = (b,h) = 1024 blocks x 256 thr. Stores go through an LDS
// transpose so global writes are 512B-contiguous per 32-lane group.
// ---------------------------------------------------------------------------
__global__ __launch_bounds__(256) void fused_energy(const float* __restrict__ x,
                                                    unsigned short* __restrict__ xsqN,
                                                    float* __restrict__ pval,
                                                    int* __restrict__ pidx) {
    int blk = blockIdx.x;
    int b = blk >> 6, h = blk & 63;
    int tid = threadIdx.x;
    int w = tid & 63, layer = tid >> 6;
    __shared__ float earr[4][4][64];
    __shared__ unsigned short tile[64][264];   // row stride 264 ush = 528B (16B-mult, bank-spread)
    float e0 = 0.f, e1 = 0.f, e2 = 0.f, e3 = 0.f;
    const float* xb = x + (size_t)b * C_ * HW_ + h * 64 + w;
#pragma unroll
    for (int i = 0; i < 8; ++i) {
        int c0 = (i * 4 + layer) * 8;
        union { unsigned short us[8]; int4 v; } u;
        float es = 0.f;
#pragma unroll
        for (int k = 0; k < 8; ++k) {
            float v = xb[(size_t)(c0 + k) * HW_];
            float s = v * v;
            es += s;
            u.us[k] = f2bf(s);
        }
        *(int4*)&tile[w][c0] = u.v;
        if ((i >> 1) == 0) e0 += es;
        else if ((i >> 1) == 1) e1 += es;
        else if ((i >> 1) == 2) e2 += es;
        else e3 += es;
    }
    earr[layer][0][w] = e0; earr[layer][1][w] = e1;
    earr[layer][2][w] = e2; earr[layer][3][w] = e3;
    __syncthreads();
    // contiguous NHWC stores: 32 lanes cover one 512B row segment
    size_t base = (size_t)(b * 64 + h) * 64 * 256;
#pragma unroll
    for (int it = 0; it < 8; ++it) {
        int row  = it * 8 + (tid >> 5);
        int col8 = (tid & 31) * 8;
        *(int4*)(xsqN + base + (size_t)row * 256 + col8) = *(int4*)&tile[row][col8];
    }
    int q = tid >> 6;
    float ev = earr[0][q][w] + earr[1][q][w] + earr[2][q][w] + earr[3][q][w];
    int ix = h * 64 + w;
#pragma unroll
    for (int off = 32; off; off >>= 1) {
        float ov = __shfl_down(ev, off);
        int   oi = __shfl_down(ix, off);
        if (ov > ev || (ov == ev && oi < ix)) { ev = ov; ix = oi; }
    }
    if ((tid & 63) == 0) {
        pval[(b * 64 + h) * 4 + q] = ev;
        pidx[(b * 64 + h) * 4 + q] = ix;
    }
}

// ---------------------------------------------------------------------------
// Final argmax over h per (b,q). grid = 64 blocks (b*4+q) x 64 thr.
// ---------------------------------------------------------------------------
__global__ __launch_bounds__(64) void energy_final(const float* __restrict__ pval,
                                                   const int* __restrict__ pidx,
                                                   int* __restrict__ lm) {
    int bq = blockIdx.x;
    int b = bq >> 2, q = bq & 3;
    int h = threadIdx.x;
    float ev = pval[(b * 64 + h) * 4 + q];
    int   ix = pidx[(b * 64 + h) * 4 + q];
#pragma unroll
    for (int off = 32; off; off >>= 1) {
        float ov = __shfl_down(ev, off);
        int   oi = __shfl_down(ix, off);
        if (ov > ev || (ov == ev && oi < ix)) { ev = ov; ix = oi; }
    }
    if (h == 0) lm[bq] = ix;
}

// ---------------------------------------------------------------------------
// Landmark value table Lval[b][c] (bf16). 16 blocks x 256 thr.
// ---------------------------------------------------------------------------
__global__ __launch_bounds__(256) void lval_kernel(const unsigned short* __restrict__ xsqN,
                                                   const int* __restrict__ lm,
                                                   unsigned short* __restrict__ Lval) {
    int t = blockIdx.x * 256 + threadIdx.x;   // b*256 + c
    int b = t >> 8, c = t & 255, q = c >> 6;
    int l = lm[b * 4 + q];
    Lval[t] = xsqN[((size_t)((b * 64 + (l >> 6)) * 64 + (l & 63))) * 256 + c];
}

// ---------------------------------------------------------------------------
// Weight pack -> fragment-ordered bf16 (unchanged, verified).
// Chunk (j,cib) = 16KB contiguous: offset (j*8+cib)*8192 ushorts.
// ---------------------------------------------------------------------------
__global__ __launch_bounds__(64) void wt_pack(const float* __restrict__ w,
                                              unsigned short* __restrict__ wa) {
    int blk  = blockIdx.x;
    int lane = threadIdx.x;
    int cog = blk & 7;
    int s   = (blk >> 3) & 1;
    int cib = (blk >> 4) & 7;
    int j   = blk >> 7;
    int co  = cog * 32 + (lane & 31);
    int k0  = cib * 32 + s * 16 + (lane >> 5) * 8;
    union { unsigned short us[8]; int4 v; } u;
#pragma unroll
    for (int jj = 0; jj < 8; ++jj) {
        int ci = k0 + jj;
        u.us[jj] = f2bf(w[(size_t)(co * 256 + ci) * 9 + j]);
    }
    *(int4*)(wa + ((size_t)blk * 64 + lane) * 8) = u.v;
}

// ---------------------------------------------------------------------------
// Conv: implicit-GEMM bf16 MFMA; BOTH operands staged through LDS.
// Block: 512 thr = 8 waves; tile 256co x 256px (4 rows). Wave: 128co x 64px.
// Grid 256 = 1 block/CU. Phase = one 3x3 tap j of one 32-ci block:
// A chunk (16KB) double-buffered, B tile (per-cib) double-buffered.
// ---------------------------------------------------------------------------
__global__ __launch_bounds__(512, 2) void conv_mfma(const unsigned short* __restrict__ xsqN,
                                                    const unsigned short* __restrict__ wa,
                                                    const float* __restrict__ bias,
                                                    const int* __restrict__ lm,
                                                    const unsigned short* __restrict__ Lval,
                                                    float* __restrict__ out) {
    int pt = blockIdx.x;              // b*16 + hq
    int b  = pt >> 4;
    int h0 = (pt & 15) * 4;
    int tid  = threadIdx.x;
    int lane = tid & 63;
    int wv   = tid >> 6;
    int wy = wv >> 2, wx = wv & 3;    // co half / image row
    int l31 = lane & 31, qh = lane >> 5;

    __shared__ unsigned short Bs[2][6 * 66 * 40];   // 63.4 KB
    __shared__ unsigned short As[2][8192];          // 32 KB

    f32x16 acc[4][2];
#pragma unroll
    for (int mt = 0; mt < 4; ++mt)
#pragma unroll
        for (int nt = 0; nt < 2; ++nt)
#pragma unroll
            for (int r = 0; r < 16; ++r) acc[mt][nt][r] = 0.f;

    int4 sv[4];   // B prefetch registers (live across one cib)
    int4 av0, av1; // A prefetch registers

    // ---- prologue: stage B(cib=0) with rect-max into Bs[0]; A chunk (0,0) into As[0]
    {
#pragma unroll
        for (int t2 = 0; t2 < 4; ++t2) {
            int idx = tid + t2 * 512;
            int4 v = {0, 0, 0, 0};
            if (idx < 1584) {
                int pr = idx / 264; int rem = idx - pr * 264;
                int pc = rem >> 2;  int part = rem & 3;
                int grow = h0 - 1 + pr, gcol = pc - 1;
                if ((unsigned)grow < 64u && (unsigned)gcol < 64u)
                    v = *(const int4*)(xsqN + (((size_t)(b * 64 + grow) * 64 + gcol) * 256 + part * 8));
            }
            sv[t2] = v;
        }
        int l = lm[b * 4 + 0];
        int hm = l >> 6, wm = l & 63;
#pragma unroll
        for (int t2 = 0; t2 < 4; ++t2) {
            int idx = tid + t2 * 512;
            if (idx < 1584) {
                int pr = idx / 264; int rem = idx - pr * 264;
                int pc = rem >> 2;  int part = rem & 3;
                int grow = h0 - 1 + pr, gcol = pc - 1;
                union { int4 v; unsigned short us[8]; } u; u.v = sv[t2];
                bool inb = ((unsigned)grow < 64u) && ((unsigned)gcol < 64u);
                if (inb && grow <= hm && gcol <= wm) {     // quadrant 0: h<=hm, w<=wm
                    union { int4 v; unsigned short us[8]; } Lu;
                    Lu.v = *(const int4*)(Lval + b * 256 + part * 8);
#pragma unroll
                    for (int k = 0; k < 8; ++k)
                        if (Lu.us[k] > u.us[k]) u.us[k] = Lu.us[k];
                }
                *(int4*)(&Bs[0][(pr * 66 + pc) * 40 + part * 8]) = u.v;
            }
        }
        const unsigned short* src = wa + tid * 16;
        av0 = *(const int4*)src;
        av1 = *(const int4*)(src + 8);
        *(int4*)(&As[0][tid * 16])     = av0;
        *(int4*)(&As[0][tid * 16 + 8]) = av1;
    }
    __syncthreads();

    for (int cib = 0; cib < 8; ++cib) {
        for (int j = 0; j < 9; ++j) {
            int p = cib * 9 + j;
            bool hasNext = (p < 71);
            // A prefetch (next phase's 16KB chunk)
            if (hasNext) {
                int jn = j + 1, cibn = cib;
                if (jn == 9) { jn = 0; cibn = cib + 1; }
                const unsigned short* src = wa + ((size_t)(jn * 8 + cibn) << 13) + tid * 16;
                av0 = *(const int4*)src;
                av1 = *(const int4*)(src + 8);
            }
            // B prefetch loads for cib+1 (issued once per cib)
            if (j == 0 && cib < 7) {
                int nc = cib + 1;
#pragma unroll
                for (int t2 = 0; t2 < 4; ++t2) {
                    int idx = tid + t2 * 512;
                    int4 v = {0, 0, 0, 0};
                    if (idx < 1584) {
                        int pr = idx / 264; int rem = idx - pr * 264;
                        int pc = rem >> 2;  int part = rem & 3;
                        int grow = h0 - 1 + pr, gcol = pc - 1;
                        if ((unsigned)grow < 64u && (unsigned)gcol < 64u)
                            v = *(const int4*)(xsqN + (((size_t)(b * 64 + grow) * 64 + gcol) * 256 + nc * 32 + part * 8));
                    }
                    sv[t2] = v;
                }
            }

            // ---- MFMA phase: A from LDS, B from LDS ----
            {
                const unsigned short* Ab = &As[p & 1][0];
                const unsigned short* Bb = &Bs[cib & 1][0];
                int dh = j / 3 - 1, dw = j % 3 - 1;
                int r  = wx + dh + 1;
                int w0 = l31 + dw + 1;
#pragma unroll
                for (int s = 0; s < 2; ++s) {
                    const bf16x8* ap = (const bf16x8*)(Ab + (((s * 8 + wy * 4) * 64 + lane) << 3));
                    bf16x8 a0 = ap[0];
                    bf16x8 a1 = ap[64];
                    bf16x8 a2 = ap[128];
                    bf16x8 a3 = ap[192];
                    bf16x8 b0 = *(const bf16x8*)(Bb + (r * 66 + w0) * 40 + s * 16 + qh * 8);
                    bf16x8 b1 = *(const bf16x8*)(Bb + (r * 66 + w0 + 32) * 40 + s * 16 + qh * 8);
                    acc[0][0] = __builtin_amdgcn_mfma_f32_32x32x16_bf16(a0, b0, acc[0][0], 0, 0, 0);
                    acc[0][1] = __builtin_amdgcn_mfma_f32_32x32x16_bf16(a0, b1, acc[0][1], 0, 0, 0);
                    acc[1][0] = __builtin_amdgcn_mfma_f32_32x32x16_bf16(a1, b0, acc[1][0], 0, 0, 0);
                    acc[1][1] = __builtin_amdgcn_mfma_f32_32x32x16_bf16(a1, b1, acc[1][1], 0, 0, 0);
                    acc[2][0] = __builtin_amdgcn_mfma_f32_32x32x16_bf16(a2, b0, acc[2][0], 0, 0, 0);
                    acc[2][1] = __builtin_amdgcn_mfma_f32_32x32x16_bf16(a2, b1, acc[2][1], 0, 0, 0);
                    acc[3][0] = __builtin_amdgcn_mfma_f32_32x32x16_bf16(a3, b0, acc[3][0], 0, 0, 0);
                    acc[3][1] = __builtin_amdgcn_mfma_f32_32x32x16_bf16(a3, b1, acc[3][1], 0, 0, 0);
                }
            }

            // B rect-max + store for cib+1 (late in the cib, into other buffer)
            if (j == 8 && cib < 7) {
                int nc = cib + 1;
                int l = lm[b * 4 + (nc >> 1)];
                int hm = l >> 6, wm = l & 63;
                bool qhle = (nc >> 1) < 2;
                bool qwle = ((nc >> 1) & 1) == 0;
                unsigned short* Bw = &Bs[(cib + 1) & 1][0];
#pragma unroll
                for (int t2 = 0; t2 < 4; ++t2) {
                    int idx = tid + t2 * 512;
                    if (idx < 1584) {
                        int pr = idx / 264; int rem = idx - pr * 264;
                        int pc = rem >> 2;  int part = rem & 3;
                        int grow = h0 - 1 + pr, gcol = pc - 1;
                        union { int4 v; unsigned short us[8]; } u; u.v = sv[t2];
                        bool inb = ((unsigned)grow < 64u) && ((unsigned)gcol < 64u);
                        bool hok = qhle ? (grow <= hm) : (grow >= hm);
                        bool wok = qwle ? (gcol <= wm) : (gcol >= wm);
                        if (inb && hok && wok) {
                            union { int4 v; unsigned short us[8]; } Lu;
                            Lu.v = *(const int4*)(Lval + b * 256 + nc * 32 + part * 8);
#pragma unroll
                            for (int k = 0; k < 8; ++k)
                                if (Lu.us[k] > u.us[k]) u.us[k] = Lu.us[k];
                        }
                        *(int4*)(&Bw[(pr * 66 + pc) * 40 + part * 8]) = u.v;
                    }
                }
            }
            // A store into the other buffer
            if (hasNext) {
                unsigned short* dst = &As[(p + 1) & 1][tid * 16];
                *(int4*)dst       = av0;
                *(int4*)(dst + 8) = av1;
            }
            __syncthreads();
        }
    }

    // ---- epilogue ----
    int h = h0 + wx;
#pragma unroll
    for (int mt = 0; mt < 4; ++mt) {
#pragma unroll
        for (int nt = 0; nt < 2; ++nt) {
#pragma unroll
            for (int r = 0; r < 16; ++r) {
                int row = (r & 3) + 8 * (r >> 2) + 4 * qh;
                int co  = wy * 128 + mt * 32 + row;
                int w   = nt * 32 + l31;
                out[(((size_t)(b * 256 + co)) * 64 + h) * 64 + w] = acc[mt][nt][r] + bias[co];
            }
        }
    }
}

// ---------------------------------------------------------------------------
extern "C" void kernel_launch(void* const* d_in, const int* in_sizes, int n_in,
                              void* d_out, int out_size, void* d_ws, size_t ws_size,
                              hipStream_t stream) {
    const float* x      = (const float*)d_in[0];
    const float* weight = (const float*)d_in[1];
    const float* bias   = (const float*)d_in[2];
    float* out = (float*)d_out;

    char* ws = (char*)d_ws;
    int*            lmp  = (int*)ws;                         // 64 ints @0
    float*          pval = (float*)(ws + 256);               // 4096 f
    int*            pidx = (int*)(ws + 256 + 16384);         // 4096 i
    unsigned short* Lval = (unsigned short*)(ws + 256 + 32768);  // 4096 ush
    unsigned short* Wa   = (unsigned short*)(ws + 49152);    // 1.18 MB
    unsigned short* xsqN = (unsigned short*)(ws + 49152 + 1179648); // NHWC bf16 33.55 MB

    hipLaunchKernelGGL(fused_energy, dim3(1024), dim3(256), 0, stream, x, xsqN, pval, pidx);
    hipLaunchKernelGGL(energy_final, dim3(64), dim3(64), 0, stream, pval, pidx, lmp);
    hipLaunchKernelGGL(lval_kernel, dim3(16), dim3(256), 0, stream, xsqN, lmp, Lval);
    hipLaunchKernelGGL(wt_pack, dim3(1152), dim3(64), 0, stream, weight, Wa);
    hipLaunchKernelGGL(conv_mfma, dim3(256), dim3(512), 0, stream, xsqN, Wa, bias, lmp, Lval, out);
}